// Round 1
// baseline (1100.034 us; speedup 1.0000x reference)
//
#include <hip/hip_runtime.h>
#include <hip/hip_bf16.h>

#define NEG_SLOPE 0.2f

// ---------- helpers ----------
__device__ __forceinline__ unsigned int enc_f32(float f) {
    unsigned int u = __float_as_uint(f);
    return (u & 0x80000000u) ? ~u : (u | 0x80000000u);
}
__device__ __forceinline__ float dec_f32(unsigned int u) {
    return (u & 0x80000000u) ? __uint_as_float(u & 0x7FFFFFFFu) : __uint_as_float(~u);
}
__device__ __forceinline__ float lrelu(float x) {
    return x > 0.f ? x : NEG_SLOPE * x;
}

// ---------- init per-layer accumulators ----------
// grid over n*C; threads with i<n also clear menc/ssum
template<int C>
__global__ void gat_init_kernel(unsigned int* __restrict__ menc,
                                float* __restrict__ ssum,
                                float* __restrict__ X,
                                const float* __restrict__ b, int n) {
    int i = blockIdx.x * blockDim.x + threadIdx.x;
    int tot = n * C;
    if (i < n) { menc[i] = 0u; ssum[i] = 0.f; }
    if (i < tot) { X[i] = b[i % C]; }
}

// ---------- node transform: h = act(in) @ W ; alpha dots ----------
template<int F_IN, int C_OUT, bool RELU_IN>
__global__ void gat_transform_kernel(const float* __restrict__ in,
                                     const float* __restrict__ W,
                                     const float* __restrict__ a_src,
                                     const float* __restrict__ a_dst,
                                     float* __restrict__ h,
                                     float* __restrict__ as,
                                     float* __restrict__ ad, int n) {
    __shared__ float sW[F_IN * C_OUT];
    __shared__ float sAs[C_OUT];
    __shared__ float sAd[C_OUT];
    for (int i = threadIdx.x; i < F_IN * C_OUT; i += blockDim.x) sW[i] = W[i];
    for (int i = threadIdx.x; i < C_OUT; i += blockDim.x) { sAs[i] = a_src[i]; sAd[i] = a_dst[i]; }
    __syncthreads();
    int i = blockIdx.x * blockDim.x + threadIdx.x;
    if (i >= n) return;
    float xin[F_IN];
#pragma unroll
    for (int f = 0; f < F_IN; ++f) {
        float v = in[(size_t)i * F_IN + f];
        if (RELU_IN) v = fmaxf(v, 0.f);
        xin[f] = v;
    }
    float s_acc = 0.f, d_acc = 0.f;
#pragma unroll
    for (int c = 0; c < C_OUT; ++c) {
        float acc = 0.f;
#pragma unroll
        for (int f = 0; f < F_IN; ++f) acc = fmaf(xin[f], sW[f * C_OUT + c], acc);
        h[(size_t)i * C_OUT + c] = acc;
        s_acc = fmaf(acc, sAs[c], s_acc);
        d_acc = fmaf(acc, sAd[c], d_acc);
    }
    as[i] = s_acc;
    ad[i] = d_acc;
}

// ---------- edge pass 1: segment max of leaky_relu(as[src]+ad[dst]) ----------
__global__ void gat_edge_max_kernel(const int* __restrict__ ei, int E, int n,
                                    const float* __restrict__ as,
                                    const float* __restrict__ ad,
                                    unsigned int* __restrict__ menc) {
    int e = blockIdx.x * blockDim.x + threadIdx.x;
    int total = E + n;
    if (e >= total) return;
    int s, d;
    if (e < E) { s = ei[e]; d = ei[E + e]; } else { s = d = e - E; }
    float logit = lrelu(as[s] + ad[d]);
    atomicMax(&menc[d], enc_f32(logit));
}

// ---------- edge pass 2: e = exp(logit - m[dst]); sum per dst; store e ----------
__global__ void gat_edge_sum_kernel(const int* __restrict__ ei, int E, int n,
                                    const float* __restrict__ as,
                                    const float* __restrict__ ad,
                                    const unsigned int* __restrict__ menc,
                                    float* __restrict__ ssum,
                                    float* __restrict__ ew) {
    int e = blockIdx.x * blockDim.x + threadIdx.x;
    int total = E + n;
    if (e >= total) return;
    int s, d;
    if (e < E) { s = ei[e]; d = ei[E + e]; } else { s = d = e - E; }
    float logit = lrelu(as[s] + ad[d]);
    float m = dec_f32(menc[d]);
    float w = expf(logit - m);
    ew[e] = w;
    atomicAdd(&ssum[d], w);
}

// ---------- edge pass 3: X[dst] += (ew/ssum[dst]) * h[src], 4-ch chunks ----------
template<int C>
__global__ void gat_edge_agg_kernel(const int* __restrict__ ei, int E, int n,
                                    const float* __restrict__ ew,
                                    const float* __restrict__ ssum,
                                    const float* __restrict__ h,
                                    float* __restrict__ X) {
    const int CHUNKS = C / 4;
    int t = blockIdx.x * blockDim.x + threadIdx.x;
    int total = (E + n) * CHUNKS;
    if (t >= total) return;
    int e = t / CHUNKS;
    int ch = t % CHUNKS;
    int s, d;
    if (e < E) { s = ei[e]; d = ei[E + e]; } else { s = d = e - E; }
    float w = ew[e] / ssum[d];
    const float4 hv = *reinterpret_cast<const float4*>(&h[(size_t)s * C + ch * 4]);
    float* xp = &X[(size_t)d * C + ch * 4];
    atomicAdd(xp + 0, w * hv.x);
    atomicAdd(xp + 1, w * hv.y);
    atomicAdd(xp + 2, w * hv.z);
    atomicAdd(xp + 3, w * hv.w);
}

// ---------- final linear 64 -> 10 ----------
__global__ void gat_linear_kernel(const float* __restrict__ X,
                                  const float* __restrict__ Wl,
                                  const float* __restrict__ bl,
                                  float* __restrict__ out, int n) {
    __shared__ float sW[64 * 10];
    __shared__ float sb[10];
    for (int i = threadIdx.x; i < 64 * 10; i += blockDim.x) sW[i] = Wl[i];
    for (int i = threadIdx.x; i < 10; i += blockDim.x) sb[i] = bl[i];
    __syncthreads();
    int i = blockIdx.x * blockDim.x + threadIdx.x;
    if (i >= n) return;
    float xin[64];
#pragma unroll
    for (int c = 0; c < 64; ++c) xin[c] = X[(size_t)i * 64 + c];
#pragma unroll
    for (int k = 0; k < 10; ++k) {
        float acc = sb[k];
#pragma unroll
        for (int c = 0; c < 64; ++c) acc = fmaf(xin[c], sW[c * 10 + k], acc);
        out[(size_t)i * 10 + k] = acc;
    }
}

extern "C" void kernel_launch(void* const* d_in, const int* in_sizes, int n_in,
                              void* d_out, int out_size, void* d_ws, size_t ws_size,
                              hipStream_t stream) {
    const float* x       = (const float*)d_in[0];
    const int*   ei      = (const int*)d_in[1];
    // d_in[2] = batch (unused)
    const float* W1      = (const float*)d_in[3];
    const float* a1_src  = (const float*)d_in[4];
    const float* a1_dst  = (const float*)d_in[5];
    const float* b1      = (const float*)d_in[6];
    const float* W2      = (const float*)d_in[7];
    const float* a2_src  = (const float*)d_in[8];
    const float* a2_dst  = (const float*)d_in[9];
    const float* b2      = (const float*)d_in[10];
    const float* Wl      = (const float*)d_in[11];
    const float* bl      = (const float*)d_in[12];
    float* out = (float*)d_out;

    const int N = in_sizes[2];        // 50000 (batch vector length)
    const int E = in_sizes[1] / 2;    // 800000
    const int ET = E + N;             // with self-loops

    // workspace layout (bytes, 256-aligned)
    char* ws = (char*)d_ws;
    size_t off = 0;
    auto alloc = [&](size_t bytes) {
        char* p = ws + off;
        off = (off + bytes + 255) & ~(size_t)255;
        return p;
    };
    float*        h     = (float*)alloc((size_t)N * 64 * 4);   // transform output (max width)
    float*        X1    = (float*)alloc((size_t)N * 16 * 4);   // layer-1 output (agg+b1)
    float*        X2    = (float*)alloc((size_t)N * 64 * 4);   // layer-2 output (agg+b2)
    float*        as    = (float*)alloc((size_t)N * 4);
    float*        ad    = (float*)alloc((size_t)N * 4);
    unsigned int* menc  = (unsigned int*)alloc((size_t)N * 4);
    float*        ssum  = (float*)alloc((size_t)N * 4);
    float*        ew    = (float*)alloc((size_t)ET * 4);
    (void)ws_size;

    const int B = 256;
    auto cdiv = [](int a, int b) { return (a + b - 1) / b; };

    // ===== layer 1 (11 -> 16) =====
    gat_init_kernel<16><<<cdiv(N * 16, B), B, 0, stream>>>(menc, ssum, X1, b1, N);
    gat_transform_kernel<11, 16, false><<<cdiv(N, B), B, 0, stream>>>(x, W1, a1_src, a1_dst, h, as, ad, N);
    gat_edge_max_kernel<<<cdiv(ET, B), B, 0, stream>>>(ei, E, N, as, ad, menc);
    gat_edge_sum_kernel<<<cdiv(ET, B), B, 0, stream>>>(ei, E, N, as, ad, menc, ssum, ew);
    gat_edge_agg_kernel<16><<<cdiv(ET * 4, B), B, 0, stream>>>(ei, E, N, ew, ssum, h, X1);

    // ===== layer 2 (16 -> 64), input relu(X1) =====
    gat_init_kernel<64><<<cdiv(N * 64, B), B, 0, stream>>>(menc, ssum, X2, b2, N);
    gat_transform_kernel<16, 64, true><<<cdiv(N, B), B, 0, stream>>>(X1, W2, a2_src, a2_dst, h, as, ad, N);
    gat_edge_max_kernel<<<cdiv(ET, B), B, 0, stream>>>(ei, E, N, as, ad, menc);
    gat_edge_sum_kernel<<<cdiv(ET, B), B, 0, stream>>>(ei, E, N, as, ad, menc, ssum, ew);
    gat_edge_agg_kernel<64><<<cdiv(ET * 16, B), B, 0, stream>>>(ei, E, N, ew, ssum, h, X2);

    // ===== final linear (64 -> 10) =====
    gat_linear_kernel<<<cdiv(N, B), B, 0, stream>>>(X2, Wl, bl, out, N);
}

// Round 2
// 341.441 us; speedup vs baseline: 3.2217x; 3.2217x over previous
//
#include <hip/hip_runtime.h>
#include <hip/hip_bf16.h>

#define NEG_SLOPE 0.2f

__device__ __forceinline__ float lrelu(float x) {
    return x > 0.f ? x : NEG_SLOPE * x;
}

// ---------- CSR build ----------
__global__ void zero_cnt_kernel(int* __restrict__ cnt, int n) {
    int i = blockIdx.x * blockDim.x + threadIdx.x;
    if (i < n) cnt[i] = 0;
}

__global__ void hist_kernel(const int* __restrict__ ei, int E, int n,
                            int* __restrict__ cnt) {
    int e = blockIdx.x * blockDim.x + threadIdx.x;
    int total = E + n;
    if (e >= total) return;
    int d = (e < E) ? ei[E + e] : (e - E);
    atomicAdd(&cnt[d], 1);
}

// single-block exclusive scan: cnt[0..n) -> row[0..n], row[n]=total
__global__ void scan_kernel(const int* __restrict__ cnt, int* __restrict__ row, int n) {
    __shared__ int part[1024];
    int t = threadIdx.x;
    const int CH = (n + 1023) / 1024;
    int base = t * CH;
    int s = 0;
    for (int i = 0; i < CH; ++i) {
        int idx = base + i;
        if (idx < n) s += cnt[idx];
    }
    part[t] = s;
    __syncthreads();
    for (int off = 1; off < 1024; off <<= 1) {
        int v = 0;
        if (t >= off) v = part[t - off];
        __syncthreads();
        if (t >= off) part[t] += v;
        __syncthreads();
    }
    int run = (t == 0) ? 0 : part[t - 1];
    for (int i = 0; i < CH; ++i) {
        int idx = base + i;
        if (idx < n) { row[idx] = run; run += cnt[idx]; }
    }
    if (t == 1023) row[n] = run;
}

__global__ void init_cur_kernel(const int* __restrict__ row, int* __restrict__ cur, int n) {
    int i = blockIdx.x * blockDim.x + threadIdx.x;
    if (i < n) cur[i] = row[i];
}

__global__ void scatter_kernel(const int* __restrict__ ei, int E, int n,
                               int* __restrict__ cur, int* __restrict__ csrc) {
    int e = blockIdx.x * blockDim.x + threadIdx.x;
    int total = E + n;
    if (e >= total) return;
    int s, d;
    if (e < E) { s = ei[e]; d = ei[E + e]; } else { s = d = e - E; }
    int slot = atomicAdd(&cur[d], 1);
    csrc[slot] = s;
}

// ---------- node transform: h = act(in) @ W ; alpha dots ----------
template<int F_IN, int C_OUT, bool RELU_IN>
__global__ void gat_transform_kernel(const float* __restrict__ in,
                                     const float* __restrict__ W,
                                     const float* __restrict__ a_src,
                                     const float* __restrict__ a_dst,
                                     float* __restrict__ h,
                                     float* __restrict__ as,
                                     float* __restrict__ ad, int n) {
    __shared__ float sW[F_IN * C_OUT];
    __shared__ float sAs[C_OUT];
    __shared__ float sAd[C_OUT];
    for (int i = threadIdx.x; i < F_IN * C_OUT; i += blockDim.x) sW[i] = W[i];
    for (int i = threadIdx.x; i < C_OUT; i += blockDim.x) { sAs[i] = a_src[i]; sAd[i] = a_dst[i]; }
    __syncthreads();
    int i = blockIdx.x * blockDim.x + threadIdx.x;
    if (i >= n) return;
    float xin[F_IN];
#pragma unroll
    for (int f = 0; f < F_IN; ++f) {
        float v = in[(size_t)i * F_IN + f];
        if (RELU_IN) v = fmaxf(v, 0.f);
        xin[f] = v;
    }
    float s_acc = 0.f, d_acc = 0.f;
#pragma unroll
    for (int c = 0; c < C_OUT; ++c) {
        float acc = 0.f;
#pragma unroll
        for (int f = 0; f < F_IN; ++f) acc = fmaf(xin[f], sW[f * C_OUT + c], acc);
        h[(size_t)i * C_OUT + c] = acc;
        s_acc = fmaf(acc, sAs[c], s_acc);
        d_acc = fmaf(acc, sAd[c], d_acc);
    }
    as[i] = s_acc;
    ad[i] = d_acc;
}

// ---------- fused per-node softmax + aggregate ----------
// SG = C lanes own one destination node; lane == channel.
template<int C>
__global__ void gat_node_agg_kernel(const int* __restrict__ row,
                                    const int* __restrict__ csrc,
                                    const float* __restrict__ as,
                                    const float* __restrict__ ad,
                                    const float* __restrict__ h,
                                    const float* __restrict__ b,
                                    float* __restrict__ X, int n) {
    const int SG = C;
    int tid = blockIdx.x * blockDim.x + threadIdx.x;
    int node = tid / SG;
    int lane = tid % SG;
    if (node >= n) return;
    int beg = row[node], end = row[node + 1];
    float add = ad[node];

    // phase 1: segment max (strided over lanes, shfl-reduce)
    float m = -3.0e38f;
    for (int i = beg + lane; i < end; i += SG)
        m = fmaxf(m, lrelu(as[csrc[i]] + add));
#pragma unroll
    for (int k = SG >> 1; k; k >>= 1) m = fmaxf(m, __shfl_xor(m, k, SG));

    // phase 2: sum of exp
    float ssum = 0.f;
    for (int i = beg + lane; i < end; i += SG)
        ssum += __expf(lrelu(as[csrc[i]] + add) - m);
#pragma unroll
    for (int k = SG >> 1; k; k >>= 1) ssum += __shfl_xor(ssum, k, SG);
    float inv = 1.f / ssum;

    // phase 3: weighted aggregate, coalesced h-row loads, plain store
    float acc = 0.f;
    for (int i = beg; i < end; ++i) {
        int s = csrc[i];                                  // broadcast load
        float w = __expf(lrelu(as[s] + add) - m) * inv;   // redundant per-lane, cheap
        acc = fmaf(w, h[(size_t)s * C + lane], acc);
    }
    X[(size_t)node * C + lane] = acc + b[lane];
}

// ---------- final linear 64 -> 10 ----------
__global__ void gat_linear_kernel(const float* __restrict__ X,
                                  const float* __restrict__ Wl,
                                  const float* __restrict__ bl,
                                  float* __restrict__ out, int n) {
    __shared__ float sW[64 * 10];
    __shared__ float sb[10];
    for (int i = threadIdx.x; i < 64 * 10; i += blockDim.x) sW[i] = Wl[i];
    for (int i = threadIdx.x; i < 10; i += blockDim.x) sb[i] = bl[i];
    __syncthreads();
    int i = blockIdx.x * blockDim.x + threadIdx.x;
    if (i >= n) return;
    float xin[64];
#pragma unroll
    for (int c = 0; c < 64; ++c) xin[c] = X[(size_t)i * 64 + c];
#pragma unroll
    for (int k = 0; k < 10; ++k) {
        float acc = sb[k];
#pragma unroll
        for (int c = 0; c < 64; ++c) acc = fmaf(xin[c], sW[c * 10 + k], acc);
        out[(size_t)i * 10 + k] = acc;
    }
}

extern "C" void kernel_launch(void* const* d_in, const int* in_sizes, int n_in,
                              void* d_out, int out_size, void* d_ws, size_t ws_size,
                              hipStream_t stream) {
    const float* x       = (const float*)d_in[0];
    const int*   ei      = (const int*)d_in[1];
    // d_in[2] = batch (unused)
    const float* W1      = (const float*)d_in[3];
    const float* a1_src  = (const float*)d_in[4];
    const float* a1_dst  = (const float*)d_in[5];
    const float* b1      = (const float*)d_in[6];
    const float* W2      = (const float*)d_in[7];
    const float* a2_src  = (const float*)d_in[8];
    const float* a2_dst  = (const float*)d_in[9];
    const float* b2      = (const float*)d_in[10];
    const float* Wl      = (const float*)d_in[11];
    const float* bl      = (const float*)d_in[12];
    float* out = (float*)d_out;

    const int N = in_sizes[2];        // 50000
    const int E = in_sizes[1] / 2;    // 800000
    const int ET = E + N;             // with self-loops

    char* ws = (char*)d_ws;
    size_t off = 0;
    auto alloc = [&](size_t bytes) {
        char* p = ws + off;
        off = (off + bytes + 255) & ~(size_t)255;
        return p;
    };
    float* h    = (float*)alloc((size_t)N * 64 * 4);
    float* X1   = (float*)alloc((size_t)N * 16 * 4);
    float* X2   = (float*)alloc((size_t)N * 64 * 4);
    float* as   = (float*)alloc((size_t)N * 4);
    float* ad   = (float*)alloc((size_t)N * 4);
    int*   row  = (int*)alloc((size_t)(N + 1) * 4);
    int*   cnt  = (int*)alloc((size_t)N * 4);
    int*   cur  = (int*)alloc((size_t)N * 4);
    int*   csrc = (int*)alloc((size_t)ET * 4);
    (void)ws_size;

    const int B = 256;
    auto cdiv = [](int a, int b) { return (a + b - 1) / b; };

    // ===== CSR build (shared by both layers) =====
    zero_cnt_kernel<<<cdiv(N, B), B, 0, stream>>>(cnt, N);
    hist_kernel<<<cdiv(ET, B), B, 0, stream>>>(ei, E, N, cnt);
    scan_kernel<<<1, 1024, 0, stream>>>(cnt, row, N);
    init_cur_kernel<<<cdiv(N, B), B, 0, stream>>>(row, cur, N);
    scatter_kernel<<<cdiv(ET, B), B, 0, stream>>>(ei, E, N, cur, csrc);

    // ===== layer 1 (11 -> 16) =====
    gat_transform_kernel<11, 16, false><<<cdiv(N, B), B, 0, stream>>>(x, W1, a1_src, a1_dst, h, as, ad, N);
    gat_node_agg_kernel<16><<<cdiv(N * 16, B), B, 0, stream>>>(row, csrc, as, ad, h, b1, X1, N);

    // ===== layer 2 (16 -> 64), input relu(X1) =====
    gat_transform_kernel<16, 64, true><<<cdiv(N, B), B, 0, stream>>>(X1, W2, a2_src, a2_dst, h, as, ad, N);
    gat_node_agg_kernel<64><<<cdiv(N * 64, B), B, 0, stream>>>(row, csrc, as, ad, h, b2, X2, N);

    // ===== final linear (64 -> 10) =====
    gat_linear_kernel<<<cdiv(N, B), B, 0, stream>>>(X2, Wl, bl, out, N);
}

// Round 3
// 310.474 us; speedup vs baseline: 3.5431x; 1.0997x over previous
//
#include <hip/hip_runtime.h>
#include <hip/hip_bf16.h>

#define NEG_SLOPE 0.2f

__device__ __forceinline__ float lrelu(float x) {
    return x > 0.f ? x : NEG_SLOPE * x;
}

// ---------- CSR build ----------
__global__ void zero_cnt_kernel(int* __restrict__ cnt, int n) {
    int i = blockIdx.x * blockDim.x + threadIdx.x;
    if (i < n) cnt[i] = 0;
}

__global__ void hist_kernel(const int* __restrict__ ei, int E, int n,
                            int* __restrict__ cnt) {
    int e = blockIdx.x * blockDim.x + threadIdx.x;
    int total = E + n;
    if (e >= total) return;
    int d = (e < E) ? ei[E + e] : (e - E);
    atomicAdd(&cnt[d], 1);
}

// single-block exclusive scan: cnt[0..n) -> row[0..n] and cur[0..n)
__global__ void scan_kernel(const int* __restrict__ cnt, int* __restrict__ row,
                            int* __restrict__ cur, int n) {
    __shared__ int part[1024];
    int t = threadIdx.x;
    const int CH = (n + 1023) / 1024;
    int base = t * CH;
    int s = 0;
    for (int i = 0; i < CH; ++i) {
        int idx = base + i;
        if (idx < n) s += cnt[idx];
    }
    part[t] = s;
    __syncthreads();
    for (int off = 1; off < 1024; off <<= 1) {
        int v = 0;
        if (t >= off) v = part[t - off];
        __syncthreads();
        if (t >= off) part[t] += v;
        __syncthreads();
    }
    int run = (t == 0) ? 0 : part[t - 1];
    for (int i = 0; i < CH; ++i) {
        int idx = base + i;
        if (idx < n) { row[idx] = run; cur[idx] = run; run += cnt[idx]; }
    }
    if (t == 1023) row[n] = run;
}

__global__ void scatter_kernel(const int* __restrict__ ei, int E, int n,
                               int* __restrict__ cur, int* __restrict__ csrc) {
    int e = blockIdx.x * blockDim.x + threadIdx.x;
    int total = E + n;
    if (e >= total) return;
    int s, d;
    if (e < E) { s = ei[e]; d = ei[E + e]; } else { s = d = e - E; }
    int slot = atomicAdd(&cur[d], 1);
    csrc[slot] = s;
}

// ---------- node transform: h = act(in) @ W ; alpha dots ----------
template<int F_IN, int C_OUT, bool RELU_IN>
__global__ void gat_transform_kernel(const float* __restrict__ in,
                                     const float* __restrict__ W,
                                     const float* __restrict__ a_src,
                                     const float* __restrict__ a_dst,
                                     float* __restrict__ h,
                                     float* __restrict__ as,
                                     float* __restrict__ ad, int n) {
    __shared__ float sW[F_IN * C_OUT];
    __shared__ float sAs[C_OUT];
    __shared__ float sAd[C_OUT];
    for (int i = threadIdx.x; i < F_IN * C_OUT; i += blockDim.x) sW[i] = W[i];
    for (int i = threadIdx.x; i < C_OUT; i += blockDim.x) { sAs[i] = a_src[i]; sAd[i] = a_dst[i]; }
    __syncthreads();
    int i = blockIdx.x * blockDim.x + threadIdx.x;
    if (i >= n) return;
    float xin[F_IN];
#pragma unroll
    for (int f = 0; f < F_IN; ++f) {
        float v = in[(size_t)i * F_IN + f];
        if (RELU_IN) v = fmaxf(v, 0.f);
        xin[f] = v;
    }
    float s_acc = 0.f, d_acc = 0.f;
#pragma unroll
    for (int c = 0; c < C_OUT; ++c) {
        float acc = 0.f;
#pragma unroll
        for (int f = 0; f < F_IN; ++f) acc = fmaf(xin[f], sW[f * C_OUT + c], acc);
        h[(size_t)i * C_OUT + c] = acc;
        s_acc = fmaf(acc, sAs[c], s_acc);
        d_acc = fmaf(acc, sAd[c], d_acc);
    }
    as[i] = s_acc;
    ad[i] = d_acc;
}

// ---------- fused per-node softmax + aggregate: one WAVE per node ----------
// Phase A: online softmax stats (all 64 lanes, edge-strided).
// Phase B: weighted aggregate; each lane owns 4 channels (float4), so
//          LPR = C/4 lanes cover one h-row and EPW = 64/LPR edges fly at once.
template<int C>
__global__ void gat_node_agg_kernel(const int* __restrict__ row,
                                    const int* __restrict__ csrc,
                                    const float* __restrict__ as,
                                    const float* __restrict__ ad,
                                    const float* __restrict__ h,
                                    const float* __restrict__ b,
                                    float* __restrict__ X, int n) {
    constexpr int LPR = C / 4;     // lanes per h-row
    constexpr int EPW = 64 / LPR;  // edges in flight
    int node = (blockIdx.x * blockDim.x + threadIdx.x) >> 6;
    int lane = threadIdx.x & 63;
    if (node >= n) return;
    int beg = row[node], end = row[node + 1];
    float add = ad[node];

    // --- phase A: online max+sum, lane-strided ---
    float m = -3.0e38f, s = 0.f;
    for (int i = beg + lane; i < end; i += 64) {
        float v = lrelu(as[csrc[i]] + add);
        if (v > m) { s *= __expf(m - v); m = v; }
        s += __expf(v - m);
    }
#pragma unroll
    for (int k = 1; k < 64; k <<= 1) {
        float mo = __shfl_xor(m, k, 64);
        float so = __shfl_xor(s, k, 64);
        float M = fmaxf(m, mo);
        s = s * __expf(m - M) + so * __expf(mo - M);
        m = M;
    }
    float inv = 1.f / s;

    // --- phase B: aggregate, EPW edges per iteration ---
    int eq = lane / LPR;
    int cl = lane % LPR;
    float4 acc = {0.f, 0.f, 0.f, 0.f};
    for (int i = beg; i < end; i += EPW) {
        int e = i + eq;
        if (e < end) {
            int src = csrc[e];
            float w = __expf(lrelu(as[src] + add) - m) * inv;
            const float4 hv = *reinterpret_cast<const float4*>(&h[(size_t)src * C + cl * 4]);
            acc.x = fmaf(w, hv.x, acc.x);
            acc.y = fmaf(w, hv.y, acc.y);
            acc.z = fmaf(w, hv.z, acc.z);
            acc.w = fmaf(w, hv.w, acc.w);
        }
    }
#pragma unroll
    for (int k = LPR; k < 64; k <<= 1) {
        acc.x += __shfl_xor(acc.x, k, 64);
        acc.y += __shfl_xor(acc.y, k, 64);
        acc.z += __shfl_xor(acc.z, k, 64);
        acc.w += __shfl_xor(acc.w, k, 64);
    }
    if (eq == 0) {
        const float4 bb = *reinterpret_cast<const float4*>(&b[cl * 4]);
        float4 o = {acc.x + bb.x, acc.y + bb.y, acc.z + bb.z, acc.w + bb.w};
        *reinterpret_cast<float4*>(&X[(size_t)node * C + cl * 4]) = o;
    }
}

// ---------- final linear 64 -> 10 ----------
__global__ void gat_linear_kernel(const float* __restrict__ X,
                                  const float* __restrict__ Wl,
                                  const float* __restrict__ bl,
                                  float* __restrict__ out, int n) {
    __shared__ float sW[64 * 10];
    __shared__ float sb[10];
    for (int i = threadIdx.x; i < 64 * 10; i += blockDim.x) sW[i] = Wl[i];
    for (int i = threadIdx.x; i < 10; i += blockDim.x) sb[i] = bl[i];
    __syncthreads();
    int i = blockIdx.x * blockDim.x + threadIdx.x;
    if (i >= n) return;
    float xin[64];
#pragma unroll
    for (int c = 0; c < 64; ++c) xin[c] = X[(size_t)i * 64 + c];
#pragma unroll
    for (int k = 0; k < 10; ++k) {
        float acc = sb[k];
#pragma unroll
        for (int c = 0; c < 64; ++c) acc = fmaf(xin[c], sW[c * 10 + k], acc);
        out[(size_t)i * 10 + k] = acc;
    }
}

extern "C" void kernel_launch(void* const* d_in, const int* in_sizes, int n_in,
                              void* d_out, int out_size, void* d_ws, size_t ws_size,
                              hipStream_t stream) {
    const float* x       = (const float*)d_in[0];
    const int*   ei      = (const int*)d_in[1];
    // d_in[2] = batch (unused)
    const float* W1      = (const float*)d_in[3];
    const float* a1_src  = (const float*)d_in[4];
    const float* a1_dst  = (const float*)d_in[5];
    const float* b1      = (const float*)d_in[6];
    const float* W2      = (const float*)d_in[7];
    const float* a2_src  = (const float*)d_in[8];
    const float* a2_dst  = (const float*)d_in[9];
    const float* b2      = (const float*)d_in[10];
    const float* Wl      = (const float*)d_in[11];
    const float* bl      = (const float*)d_in[12];
    float* out = (float*)d_out;

    const int N = in_sizes[2];        // 50000
    const int E = in_sizes[1] / 2;    // 800000
    const int ET = E + N;             // with self-loops

    char* ws = (char*)d_ws;
    size_t off = 0;
    auto alloc = [&](size_t bytes) {
        char* p = ws + off;
        off = (off + bytes + 255) & ~(size_t)255;
        return p;
    };
    float* h    = (float*)alloc((size_t)N * 64 * 4);
    float* X1   = (float*)alloc((size_t)N * 16 * 4);
    float* X2   = (float*)alloc((size_t)N * 64 * 4);
    float* as   = (float*)alloc((size_t)N * 4);
    float* ad   = (float*)alloc((size_t)N * 4);
    int*   row  = (int*)alloc((size_t)(N + 1) * 4);
    int*   cnt  = (int*)alloc((size_t)N * 4);
    int*   cur  = (int*)alloc((size_t)N * 4);
    int*   csrc = (int*)alloc((size_t)ET * 4);
    (void)ws_size;

    const int B = 256;
    auto cdiv = [](int a, int b) { return (a + b - 1) / b; };

    // ===== CSR build (shared by both layers) =====
    zero_cnt_kernel<<<cdiv(N, B), B, 0, stream>>>(cnt, N);
    hist_kernel<<<cdiv(ET, B), B, 0, stream>>>(ei, E, N, cnt);
    scan_kernel<<<1, 1024, 0, stream>>>(cnt, row, cur, N);
    scatter_kernel<<<cdiv(ET, B), B, 0, stream>>>(ei, E, N, cur, csrc);

    // ===== layer 1 (11 -> 16) =====
    gat_transform_kernel<11, 16, false><<<cdiv(N, B), B, 0, stream>>>(x, W1, a1_src, a1_dst, h, as, ad, N);
    gat_node_agg_kernel<16><<<cdiv(N * 64, B), B, 0, stream>>>(row, csrc, as, ad, h, b1, X1, N);

    // ===== layer 2 (16 -> 64), input relu(X1) =====
    gat_transform_kernel<16, 64, true><<<cdiv(N, B), B, 0, stream>>>(X1, W2, a2_src, a2_dst, h, as, ad, N);
    gat_node_agg_kernel<64><<<cdiv(N * 64, B), B, 0, stream>>>(row, csrc, as, ad, h, b2, X2, N);

    // ===== final linear (64 -> 10) =====
    gat_linear_kernel<<<cdiv(N, B), B, 0, stream>>>(X2, Wl, bl, out, N);
}

// Round 4
// 199.798 us; speedup vs baseline: 5.5057x; 1.5539x over previous
//
#include <hip/hip_runtime.h>
#include <hip/hip_bf16.h>

#define NEG_SLOPE 0.2f

__device__ __forceinline__ float lrelu(float x) {
    return x > 0.f ? x : NEG_SLOPE * x;
}

// ---------- CSR build ----------
__global__ void zero_cnt_kernel(int* __restrict__ cnt, int n) {
    int i = blockIdx.x * blockDim.x + threadIdx.x;
    if (i < n) cnt[i] = 0;
}

__global__ void hist_kernel(const int* __restrict__ ei, int E, int n,
                            int* __restrict__ cnt) {
    int e = blockIdx.x * blockDim.x + threadIdx.x;
    int total = E + n;
    if (e >= total) return;
    int d = (e < E) ? ei[E + e] : (e - E);
    atomicAdd(&cnt[d], 1);
}

// ---- hierarchical scan: A) per-block sums ----
__global__ void blocksum_kernel(const int* __restrict__ cnt, int* __restrict__ bsum, int n) {
    __shared__ int sdata[256];
    int i = blockIdx.x * 256 + threadIdx.x;
    sdata[threadIdx.x] = (i < n) ? cnt[i] : 0;
    __syncthreads();
    for (int off = 128; off; off >>= 1) {
        if (threadIdx.x < off) sdata[threadIdx.x] += sdata[threadIdx.x + off];
        __syncthreads();
    }
    if (threadIdx.x == 0) bsum[blockIdx.x] = sdata[0];
}

// ---- B) single-block exclusive scan of block sums (nb <= 1024) ----
__global__ void bscan_kernel(int* __restrict__ bsum, int nb) {
    __shared__ int sdata[1024];
    int t = threadIdx.x;
    int v = (t < nb) ? bsum[t] : 0;
    sdata[t] = v;
    __syncthreads();
    for (int off = 1; off < 1024; off <<= 1) {
        int u = (t >= off) ? sdata[t - off] : 0;
        __syncthreads();
        sdata[t] += u;
        __syncthreads();
    }
    if (t < nb) bsum[t] = sdata[t] - v;  // exclusive
}

// ---- C) per-block local scan + offset -> row, cur ----
__global__ void localscan_kernel(const int* __restrict__ cnt, const int* __restrict__ bsum,
                                 int* __restrict__ row, int* __restrict__ cur, int n) {
    __shared__ int sdata[256];
    int i = blockIdx.x * 256 + threadIdx.x;
    int v = (i < n) ? cnt[i] : 0;
    sdata[threadIdx.x] = v;
    __syncthreads();
    for (int off = 1; off < 256; off <<= 1) {
        int u = (threadIdx.x >= off) ? sdata[threadIdx.x - off] : 0;
        __syncthreads();
        sdata[threadIdx.x] += u;
        __syncthreads();
    }
    if (i < n) {
        int excl = bsum[blockIdx.x] + sdata[threadIdx.x] - v;
        row[i] = excl;
        cur[i] = excl;
        if (i == n - 1) row[n] = excl + v;
    }
}

__global__ void scatter_kernel(const int* __restrict__ ei, int E, int n,
                               int* __restrict__ cur, int* __restrict__ csrc) {
    int e = blockIdx.x * blockDim.x + threadIdx.x;
    int total = E + n;
    if (e >= total) return;
    int s, d;
    if (e < E) { s = ei[e]; d = ei[E + e]; } else { s = d = e - E; }
    int slot = atomicAdd(&cur[d], 1);
    csrc[slot] = s;
}

// ---------- node transform: h = act(in) @ W ; alpha dots ----------
template<int F_IN, int C_OUT, bool RELU_IN>
__global__ void gat_transform_kernel(const float* __restrict__ in,
                                     const float* __restrict__ W,
                                     const float* __restrict__ a_src,
                                     const float* __restrict__ a_dst,
                                     float* __restrict__ h,
                                     float* __restrict__ as,
                                     float* __restrict__ ad, int n) {
    __shared__ float sW[F_IN * C_OUT];
    __shared__ float sAs[C_OUT];
    __shared__ float sAd[C_OUT];
    for (int i = threadIdx.x; i < F_IN * C_OUT; i += blockDim.x) sW[i] = W[i];
    for (int i = threadIdx.x; i < C_OUT; i += blockDim.x) { sAs[i] = a_src[i]; sAd[i] = a_dst[i]; }
    __syncthreads();
    int i = blockIdx.x * blockDim.x + threadIdx.x;
    if (i >= n) return;
    float xin[F_IN];
#pragma unroll
    for (int f = 0; f < F_IN; ++f) {
        float v = in[(size_t)i * F_IN + f];
        if (RELU_IN) v = fmaxf(v, 0.f);
        xin[f] = v;
    }
    float s_acc = 0.f, d_acc = 0.f;
#pragma unroll
    for (int c = 0; c < C_OUT; ++c) {
        float acc = 0.f;
#pragma unroll
        for (int f = 0; f < F_IN; ++f) acc = fmaf(xin[f], sW[f * C_OUT + c], acc);
        h[(size_t)i * C_OUT + c] = acc;
        s_acc = fmaf(acc, sAs[c], s_acc);
        d_acc = fmaf(acc, sAd[c], d_acc);
    }
    as[i] = s_acc;
    ad[i] = d_acc;
}

// ---------- fused per-node softmax + aggregate: one WAVE per node ----------
template<int C>
__global__ void gat_node_agg_kernel(const int* __restrict__ row,
                                    const int* __restrict__ csrc,
                                    const float* __restrict__ as,
                                    const float* __restrict__ ad,
                                    const float* __restrict__ h,
                                    const float* __restrict__ b,
                                    float* __restrict__ X, int n) {
    constexpr int LPR = C / 4;     // lanes per h-row
    constexpr int EPW = 64 / LPR;  // edges in flight
    int node = (blockIdx.x * blockDim.x + threadIdx.x) >> 6;
    int lane = threadIdx.x & 63;
    if (node >= n) return;
    int beg = row[node], end = row[node + 1];
    float add = ad[node];

    // --- phase A: online max+sum, lane-strided ---
    float m = -3.0e38f, s = 0.f;
    for (int i = beg + lane; i < end; i += 64) {
        float v = lrelu(as[csrc[i]] + add);
        if (v > m) { s *= __expf(m - v); m = v; }
        s += __expf(v - m);
    }
#pragma unroll
    for (int k = 1; k < 64; k <<= 1) {
        float mo = __shfl_xor(m, k, 64);
        float so = __shfl_xor(s, k, 64);
        float M = fmaxf(m, mo);
        s = s * __expf(m - M) + so * __expf(mo - M);
        m = M;
    }
    float inv = 1.f / s;

    // --- phase B: aggregate, EPW edges per iteration ---
    int eq = lane / LPR;
    int cl = lane % LPR;
    float4 acc = {0.f, 0.f, 0.f, 0.f};
    for (int i = beg; i < end; i += EPW) {
        int e = i + eq;
        if (e < end) {
            int src = csrc[e];
            float w = __expf(lrelu(as[src] + add) - m) * inv;
            const float4 hv = *reinterpret_cast<const float4*>(&h[(size_t)src * C + cl * 4]);
            acc.x = fmaf(w, hv.x, acc.x);
            acc.y = fmaf(w, hv.y, acc.y);
            acc.z = fmaf(w, hv.z, acc.z);
            acc.w = fmaf(w, hv.w, acc.w);
        }
    }
#pragma unroll
    for (int k = LPR; k < 64; k <<= 1) {
        acc.x += __shfl_xor(acc.x, k, 64);
        acc.y += __shfl_xor(acc.y, k, 64);
        acc.z += __shfl_xor(acc.z, k, 64);
        acc.w += __shfl_xor(acc.w, k, 64);
    }
    if (eq == 0) {
        const float4 bb = *reinterpret_cast<const float4*>(&b[cl * 4]);
        float4 o = {acc.x + bb.x, acc.y + bb.y, acc.z + bb.z, acc.w + bb.w};
        *reinterpret_cast<float4*>(&X[(size_t)node * C + cl * 4]) = o;
    }
}

// ---------- final linear 64 -> 10 ----------
__global__ void gat_linear_kernel(const float* __restrict__ X,
                                  const float* __restrict__ Wl,
                                  const float* __restrict__ bl,
                                  float* __restrict__ out, int n) {
    __shared__ float sW[64 * 10];
    __shared__ float sb[10];
    for (int i = threadIdx.x; i < 64 * 10; i += blockDim.x) sW[i] = Wl[i];
    for (int i = threadIdx.x; i < 10; i += blockDim.x) sb[i] = bl[i];
    __syncthreads();
    int i = blockIdx.x * blockDim.x + threadIdx.x;
    if (i >= n) return;
    float xin[64];
#pragma unroll
    for (int c = 0; c < 64; ++c) xin[c] = X[(size_t)i * 64 + c];
#pragma unroll
    for (int k = 0; k < 10; ++k) {
        float acc = sb[k];
#pragma unroll
        for (int c = 0; c < 64; ++c) acc = fmaf(xin[c], sW[c * 10 + k], acc);
        out[(size_t)i * 10 + k] = acc;
    }
}

extern "C" void kernel_launch(void* const* d_in, const int* in_sizes, int n_in,
                              void* d_out, int out_size, void* d_ws, size_t ws_size,
                              hipStream_t stream) {
    const float* x       = (const float*)d_in[0];
    const int*   ei      = (const int*)d_in[1];
    // d_in[2] = batch (unused)
    const float* W1      = (const float*)d_in[3];
    const float* a1_src  = (const float*)d_in[4];
    const float* a1_dst  = (const float*)d_in[5];
    const float* b1      = (const float*)d_in[6];
    const float* W2      = (const float*)d_in[7];
    const float* a2_src  = (const float*)d_in[8];
    const float* a2_dst  = (const float*)d_in[9];
    const float* b2      = (const float*)d_in[10];
    const float* Wl      = (const float*)d_in[11];
    const float* bl      = (const float*)d_in[12];
    float* out = (float*)d_out;

    const int N = in_sizes[2];        // 50000
    const int E = in_sizes[1] / 2;    // 800000
    const int ET = E + N;             // with self-loops

    char* ws = (char*)d_ws;
    size_t off = 0;
    auto alloc = [&](size_t bytes) {
        char* p = ws + off;
        off = (off + bytes + 255) & ~(size_t)255;
        return p;
    };
    float* h    = (float*)alloc((size_t)N * 64 * 4);
    float* X1   = (float*)alloc((size_t)N * 16 * 4);
    float* X2   = (float*)alloc((size_t)N * 64 * 4);
    float* as   = (float*)alloc((size_t)N * 4);
    float* ad   = (float*)alloc((size_t)N * 4);
    int*   row  = (int*)alloc((size_t)(N + 1) * 4);
    int*   cnt  = (int*)alloc((size_t)N * 4);
    int*   cur  = (int*)alloc((size_t)N * 4);
    int*   csrc = (int*)alloc((size_t)ET * 4);
    int*   bsum = (int*)alloc((size_t)1024 * 4);
    (void)ws_size;

    const int B = 256;
    auto cdiv = [](int a, int b) { return (a + b - 1) / b; };
    const int NB = cdiv(N, 256);   // scan blocks (196 for N=50000)

    // ===== CSR build (shared by both layers) =====
    zero_cnt_kernel<<<cdiv(N, B), B, 0, stream>>>(cnt, N);
    hist_kernel<<<cdiv(ET, B), B, 0, stream>>>(ei, E, N, cnt);
    blocksum_kernel<<<NB, 256, 0, stream>>>(cnt, bsum, N);
    bscan_kernel<<<1, 1024, 0, stream>>>(bsum, NB);
    localscan_kernel<<<NB, 256, 0, stream>>>(cnt, bsum, row, cur, N);
    scatter_kernel<<<cdiv(ET, B), B, 0, stream>>>(ei, E, N, cur, csrc);

    // ===== layer 1 (11 -> 16) =====
    gat_transform_kernel<11, 16, false><<<cdiv(N, B), B, 0, stream>>>(x, W1, a1_src, a1_dst, h, as, ad, N);
    gat_node_agg_kernel<16><<<cdiv(N * 64, B), B, 0, stream>>>(row, csrc, as, ad, h, b1, X1, N);

    // ===== layer 2 (16 -> 64), input relu(X1) =====
    gat_transform_kernel<16, 64, true><<<cdiv(N, B), B, 0, stream>>>(X1, W2, a2_src, a2_dst, h, as, ad, N);
    gat_node_agg_kernel<64><<<cdiv(N * 64, B), B, 0, stream>>>(row, csrc, as, ad, h, b2, X2, N);

    // ===== final linear (64 -> 10) =====
    gat_linear_kernel<<<cdiv(N, B), B, 0, stream>>>(X2, Wl, bl, out, N);
}